// Round 10
// baseline (173.521 us; speedup 1.0000x reference)
//
#include <hip/hip_runtime.h>
#include <cmath>

#define C_DIM 256
#define E_DIM 128
#define S_DIM 4096

typedef __bf16 bf16x8 __attribute__((ext_vector_type(8)));
typedef float  f32x4  __attribute__((ext_vector_type(4)));
typedef short  s16x8  __attribute__((ext_vector_type(8)));
typedef short  s16x4  __attribute__((ext_vector_type(4)));

__device__ __forceinline__ unsigned short f2bf(float f) {
  union { float f; unsigned u; } v; v.f = f;
  unsigned r = v.u + 0x7FFFu + ((v.u >> 16) & 1u);
  return (unsigned short)(r >> 16);
}
__device__ __forceinline__ unsigned short f2bf_tr(float f) {  // truncating
  union { float f; unsigned u; } v; v.f = f;
  return (unsigned short)(v.u >> 16);
}
// pack 4 floats -> 4 fp8 e4m3 bytes
__device__ __forceinline__ unsigned pk8(float x0, float x1, float x2, float x3) {
  int d = __builtin_amdgcn_cvt_pk_fp8_f32(x0, x1, 0, false);
  d = __builtin_amdgcn_cvt_pk_fp8_f32(x2, x3, d, true);
  return (unsigned)d;
}

// ---------------------------------------------------------------------------
// Kernel 0: cast weights fp32 -> bf16. [Wth 32768][Wph 32768][Wproj 65536].
// ---------------------------------------------------------------------------
__global__ __launch_bounds__(256) void cast_w_kernel(
    const float* __restrict__ Wth, const float* __restrict__ Wph,
    const float* __restrict__ Wpr, short* __restrict__ Wb) {
  int t = blockIdx.x * 256 + threadIdx.x;
  int i = t * 4;
  const float* src; int j;
  if (i < 32768)      { src = Wth; j = i; }
  else if (i < 65536) { src = Wph; j = i - 32768; }
  else                { src = Wpr; j = i - 65536; }
  float4 v = *(const float4*)(src + j);
  s16x4 o;
  o[0] = (short)f2bf(v.x); o[1] = (short)f2bf(v.y);
  o[2] = (short)f2bf(v.z); o[3] = (short)f2bf(v.w);
  *(s16x4*)(Wb + i) = o;
}

// ---------------------------------------------------------------------------
// Kernel 1 (MFMA): Q[s,e] = qscale * sum_c Wth[e,c] x[c,s]; K likewise.
// Emits fp8 e4m3 copy of x (the attention V). grid 512.
// ---------------------------------------------------------------------------
__global__ __launch_bounds__(256) void mix_kernel(
    const float* __restrict__ x, const short* __restrict__ Wb,
    short* __restrict__ Qg, short* __restrict__ Kg,
    unsigned char* __restrict__ Xb8, float qscale) {
  __shared__ short lxT[32 * C_DIM];   // [s][c] bf16, swizzled, 16 KB
  int bid = blockIdx.x;
  int n = bid >> 7, s0 = (bid & 127) * 32;
  int tid = threadIdx.x;
  int wid = tid >> 6, lane = tid & 63, l15 = lane & 15, l4 = lane >> 4;

  { // stage x^T tile (bf16 in LDS) + emit fp8 V copy
    int cp = tid >> 1, su = tid & 1;
    const float* r0 = x + ((size_t)n * C_DIM + 2 * cp) * S_DIM + s0 + su * 16;
    const float* r1 = r0 + S_DIM;
    float a0[16], a1[16];
    #pragma unroll
    for (int j = 0; j < 4; ++j) {
      *(float4*)(a0 + 4 * j) = *(const float4*)(r0 + 4 * j);
      *(float4*)(a1 + 4 * j) = *(const float4*)(r1 + 4 * j);
    }
    unsigned char* xb0 = Xb8 + ((size_t)n * C_DIM + 2 * cp) * S_DIM + s0 + su * 16;
    uint4 w0, w1;
    w0.x = pk8(a0[0], a0[1], a0[2], a0[3]);
    w0.y = pk8(a0[4], a0[5], a0[6], a0[7]);
    w0.z = pk8(a0[8], a0[9], a0[10], a0[11]);
    w0.w = pk8(a0[12], a0[13], a0[14], a0[15]);
    w1.x = pk8(a1[0], a1[1], a1[2], a1[3]);
    w1.y = pk8(a1[4], a1[5], a1[6], a1[7]);
    w1.z = pk8(a1[8], a1[9], a1[10], a1[11]);
    w1.w = pk8(a1[12], a1[13], a1[14], a1[15]);
    *(uint4*)(xb0) = w0;
    *(uint4*)(xb0 + S_DIM) = w1;
    #pragma unroll
    for (int j = 0; j < 16; ++j) {
      int s = su * 16 + j;
      unsigned d = (unsigned)f2bf(a0[j]) | ((unsigned)f2bf(a1[j]) << 16);
      *(unsigned*)((char*)lxT + s * 512 + ((4 * cp) ^ ((s & 7) << 4))) = d;
    }
  }
  __syncthreads();

  const short* Wq = Wb;
  const short* Wk = Wb + 32768;
  const f32x4 fzero = {0.f, 0.f, 0.f, 0.f};
  f32x4 accQ[2][2], accK[2][2];
  #pragma unroll
  for (int a = 0; a < 2; ++a)
    #pragma unroll
    for (int b = 0; b < 2; ++b) { accQ[a][b] = fzero; accK[a][b] = fzero; }

  #pragma unroll 2
  for (int kk = 0; kk < 8; ++kk) {
    bf16x8 bfr[2];
    #pragma unroll
    for (int nf = 0; nf < 2; ++nf) {
      int s = nf * 16 + l15;
      bfr[nf] = *(const bf16x8*)((char*)lxT + s * 512 +
                                 ((kk * 64 + l4 * 16) ^ ((s & 7) << 4)));
    }
    #pragma unroll
    for (int mf = 0; mf < 2; ++mf) {
      int e = wid * 32 + mf * 16 + l15;
      bf16x8 aq = *(const bf16x8*)(Wq + e * C_DIM + kk * 32 + l4 * 8);
      bf16x8 ak = *(const bf16x8*)(Wk + e * C_DIM + kk * 32 + l4 * 8);
      #pragma unroll
      for (int nf = 0; nf < 2; ++nf) {
        accQ[mf][nf] = __builtin_amdgcn_mfma_f32_16x16x32_bf16(aq, bfr[nf], accQ[mf][nf], 0, 0, 0);
        accK[mf][nf] = __builtin_amdgcn_mfma_f32_16x16x32_bf16(ak, bfr[nf], accK[mf][nf], 0, 0, 0);
      }
    }
  }

  #pragma unroll
  for (int mf = 0; mf < 2; ++mf) {
    #pragma unroll
    for (int nf = 0; nf < 2; ++nf) {
      int e = wid * 32 + mf * 16 + l4 * 4;
      int s = s0 + nf * 16 + l15;
      s16x4 pq, pk;
      #pragma unroll
      for (int r = 0; r < 4; ++r) {
        pq[r] = (short)f2bf(accQ[mf][nf][r] * qscale);
        pk[r] = (short)f2bf(accK[mf][nf][r]);
      }
      *(s16x4*)(Qg + ((size_t)n * S_DIM + s) * E_DIM + e) = pq;
      *(s16x4*)(Kg + ((size_t)n * S_DIM + s) * E_DIM + e) = pk;
    }
  }
}

// ---------------------------------------------------------------------------
// Kernel 2: flash attention, UNIFIED-ROLE 4-wave blocks, 2 blocks/CU.
// 32 q-rows/block, grid 512 = 4 n x 128 q-tiles (XCD-pinned batches).
// Per window (64 t): every wave: [V issue | K commit | QKT(t-quarter) + P fp8]
// BARRIER [PV(c-quarter, fp8 MFMA) | K load]. One lgkm-barrier per window;
// cross-block TLP fills the serial tails. Q/K bf16, V/P fp8 e4m3.
// ---------------------------------------------------------------------------

#define RAW_BARRIER()                                                         \
  asm volatile("s_waitcnt lgkmcnt(0)" ::: "memory");                          \
  __builtin_amdgcn_s_barrier();

#define K_LOAD(dst, TI)                                                       \
  _Pragma("unroll")                                                           \
  for (int jj = 0; jj < 4; ++jj)                                              \
    dst[jj] = *(const s16x8*)(Kb + (size_t)((TI) * 64 + kr + 16 * jj) * E_DIM + kc * 8);

#define K_COMMIT(src, B)                                                      \
  {                                                                           \
    char* kw = (char*)lK + (B) * 16384;                                       \
    _Pragma("unroll")                                                         \
    for (int jj = 0; jj < 4; ++jj) {                                          \
      int r = kr + 16 * jj;                                                   \
      *(s16x8*)(kw + r * 256 + ((kc * 16) ^ ((r & 7) << 4))) = src[jj];       \
    }                                                                         \
  }

#define V_ISSUE(TI)                                                           \
  _Pragma("unroll")                                                           \
  for (int kk = 0; kk < 2; ++kk)                                              \
    _Pragma("unroll")                                                         \
    for (int ct = 0; ct < 4; ++ct)                                            \
      vpre[kk * 4 + ct] = *(const long long*)(                                \
          Vb + (size_t)(cq * 64 + ct * 16 + l15) * S_DIM + (TI) * 64 + kk * 32 + l4 * 8);

#define QKT_WIN(B)                                                            \
  {                                                                           \
    const char* kb = (const char*)lK + (B) * 16384;                           \
    char* pw = (char*)lP + (B) * 2048;                                        \
    f32x4 sc0 = fzero, sc1 = fzero;                                           \
    int trow = tq * 16 + l15;                                                 \
    int swz = (trow & 7) << 4;                                                \
    __builtin_amdgcn_s_setprio(1);                                            \
    _Pragma("unroll")                                                         \
    for (int ec = 0; ec < 4; ++ec) {                                          \
      bf16x8 kf = *(const bf16x8*)(kb + trow * 256 + ((ec * 64 + l4 * 16) ^ swz)); \
      sc0 = __builtin_amdgcn_mfma_f32_16x16x32_bf16(kf, qf0[ec], sc0, 0, 0, 0); \
      sc1 = __builtin_amdgcn_mfma_f32_16x16x32_bf16(kf, qf1[ec], sc1, 0, 0, 0); \
    }                                                                         \
    __builtin_amdgcn_s_setprio(0);                                            \
    int tb = tq * 16 + l4 * 4;                                                \
    {                                                                         \
      float p0 = __builtin_amdgcn_exp2f(sc0[0]);                              \
      float p1 = __builtin_amdgcn_exp2f(sc0[1]);                              \
      float p2 = __builtin_amdgcn_exp2f(sc0[2]);                              \
      float p3 = __builtin_amdgcn_exp2f(sc0[3]);                              \
      lsum0 += (p0 + p1) + (p2 + p3);                                         \
      int q = l15;                                                            \
      *(int*)(pw + q * 64 + (tb ^ ((q & 7) << 3))) = (int)pk8(p0, p1, p2, p3);\
    }                                                                         \
    {                                                                         \
      float p0 = __builtin_amdgcn_exp2f(sc1[0]);                              \
      float p1 = __builtin_amdgcn_exp2f(sc1[1]);                              \
      float p2 = __builtin_amdgcn_exp2f(sc1[2]);                              \
      float p3 = __builtin_amdgcn_exp2f(sc1[3]);                              \
      lsum1 += (p0 + p1) + (p2 + p3);                                         \
      int q = 16 + l15;                                                       \
      *(int*)(pw + q * 64 + (tb ^ ((q & 7) << 3))) = (int)pk8(p0, p1, p2, p3);\
    }                                                                         \
  }

#define PV_WIN(B)                                                             \
  {                                                                           \
    const char* pr = (const char*)lP + (B) * 2048;                            \
    _Pragma("unroll")                                                         \
    for (int kk = 0; kk < 2; ++kk) {                                          \
      int tswz = (kk * 32 + l4 * 8) ^ ((l15 & 7) << 3);                       \
      long long pf0 = *(const long long*)(pr + l15 * 64 + tswz);              \
      long long pf1 = *(const long long*)(pr + (16 + l15) * 64 + tswz);       \
      __builtin_amdgcn_s_setprio(1);                                          \
      _Pragma("unroll")                                                       \
      for (int ct = 0; ct < 4; ++ct) {                                        \
        long long vf = vpre[kk * 4 + ct];                                     \
        acc0[ct] = __builtin_amdgcn_mfma_f32_16x16x32_fp8_fp8(pf0, vf, acc0[ct], 0, 0, 0); \
        acc1[ct] = __builtin_amdgcn_mfma_f32_16x16x32_fp8_fp8(pf1, vf, acc1[ct], 0, 0, 0); \
      }                                                                       \
      __builtin_amdgcn_s_setprio(0);                                          \
    }                                                                         \
  }

__global__ __launch_bounds__(256, 2) void attn_kernel(
    const short* __restrict__ Qg, const short* __restrict__ Kg,
    const unsigned char* __restrict__ Xb8, short* __restrict__ Yg) {
  __shared__ short lK[2 * 64 * E_DIM];   // 32 KB, dbuf, bf16 swizzled [t][e]
  __shared__ long long lP8[2 * 32 * 8];  //  4 KB, dbuf, fp8 [q][t] swizzled
  __shared__ float lsred[4 * 32];        // 512 B
  char* lP = (char*)lP8;

  int bid = blockIdx.x;
  int xcd = bid & 7;                 // dispatch round-robins XCDs
  int n   = xcd >> 1;                // batch pinned to an XCD pair
  int qt  = ((xcd & 1) << 6) | (bid >> 3);   // 0..127
  int s0  = qt * 32;

  int tid = threadIdx.x;
  int wid = tid >> 6, lane = tid & 63;
  int l15 = lane & 15, l4 = lane >> 4;

  const short* Kb = Kg + (size_t)n * S_DIM * E_DIM;
  const unsigned char* Vb = Xb8 + (size_t)n * (size_t)C_DIM * S_DIM;

  const f32x4 fzero = {0.f, 0.f, 0.f, 0.f};

  int tq = wid;                 // QKT t-quarter (16 t of the 64-t window)
  int cq = wid;                 // PV  c-quarter (64 c of 256)
  int kr = tid >> 4, kc = tid & 15;   // K staging (all 256 threads)

  // ---- persistent state (every wave holds both roles' state) ----
  bf16x8 qf0[4], qf1[4];        // Q frags, q = s0 + {0,16} + l15
  float lsum0 = 0.f, lsum1 = 0.f;
  f32x4 acc0[4], acc1[4];       // y acc, c = cq*64 + ct*16 + l15
  s16x8 kpreE[4], kpreO[4];     // K staging regs (even/odd tile parity)
  long long vpre[8];            // V fp8 frags for the current window

  {
    const short* qp0 = Qg + ((size_t)n * S_DIM + s0 + l15) * E_DIM + l4 * 8;
    const short* qp1 = qp0 + 16 * E_DIM;
    #pragma unroll
    for (int ec = 0; ec < 4; ++ec) {
      qf0[ec] = *(const bf16x8*)(qp0 + ec * 32);
      qf1[ec] = *(const bf16x8*)(qp1 + ec * 32);
    }
  }
  #pragma unroll
  for (int ct = 0; ct < 4; ++ct) { acc0[ct] = fzero; acc1[ct] = fzero; }

  // prologue: stage K0 -> buf0; prefetch K1 -> kpreO
  K_LOAD(kpreE, 0);
  K_COMMIT(kpreE, 0);
  K_LOAD(kpreO, 1);
  RAW_BARRIER();

  // ---- main: 64 windows of 64 t, ONE lgkm-barrier each ----
  for (int j = 0; j < 32; ++j) {
    int i0 = 2 * j;
    // window i0 (even): lK/lP buf 0
    V_ISSUE(i0);
    K_COMMIT(kpreO, 1);                 // K tile i0+1 -> buf1
    QKT_WIN(0);
    RAW_BARRIER();
    PV_WIN(0);
    if (j < 31) K_LOAD(kpreE, i0 + 2);
    // window i0+1 (odd): lK/lP buf 1
    V_ISSUE(i0 + 1);
    if (j < 31) K_COMMIT(kpreE, 0);     // K tile i0+2 -> buf0
    QKT_WIN(1);
    RAW_BARRIER();
    PV_WIN(1);
    if (j < 31) K_LOAD(kpreO, i0 + 3);
  }

  // ---- epilogue ----
  {
    float v0 = lsum0, v1 = lsum1;
    v0 += __shfl_xor(v0, 16); v0 += __shfl_xor(v0, 32);
    v1 += __shfl_xor(v1, 16); v1 += __shfl_xor(v1, 32);
    if (lane < 16) {
      lsred[wid * 32 + l15] = v0;
      lsred[wid * 32 + 16 + l15] = v1;
    }
  }
  __syncthreads();

  short* yst = lK;   // reuse as [32 q][256 c] bf16, swizzled rows (16 KB)
  #pragma unroll
  for (int qs = 0; qs < 2; ++qs) {
    #pragma unroll
    for (int r = 0; r < 4; ++r) {
      int q = qs * 16 + l4 * 4 + r;
      float tot = lsred[q] + lsred[32 + q] + lsred[64 + q] + lsred[96 + q];
      float rl = 1.0f / tot;
      #pragma unroll
      for (int ct = 0; ct < 4; ++ct) {
        int c = cq * 64 + ct * 16 + l15;
        float y = (qs ? acc1[ct][r] : acc0[ct][r]) * rl;
        *(unsigned short*)((char*)yst + q * 512 + ((c * 2) ^ ((q & 7) << 4))) =
            f2bf_tr(y);
      }
    }
  }
  __syncthreads();

  int rr = tid >> 3, chb = tid & 7;
  #pragma unroll
  for (int it = 0; it < 4; ++it) {
    int ch = chb + 8 * it;
    s16x8 v = *(const s16x8*)((char*)yst + rr * 512 + ((ch * 16) ^ ((rr & 7) << 4)));
    *(s16x8*)(Yg + ((size_t)n * S_DIM + s0 + rr) * C_DIM + ch * 8) = v;
  }
}

// ---------------------------------------------------------------------------
// Kernel 3 (MFMA, zero LDS): out[o,s] = x[o,s] + sum_c Wp[o,c] y[s,c]
// ---------------------------------------------------------------------------
__global__ __launch_bounds__(256) void proj_kernel(
    const short* __restrict__ Yg, const short* __restrict__ Wpb,
    const float* __restrict__ x, float* __restrict__ out) {
  int bid = blockIdx.x;
  int n = bid >> 7, s0 = (bid & 127) * 32;
  int tid = threadIdx.x;
  int wid = tid >> 6, lane = tid & 63, l15 = lane & 15, l4 = lane >> 4;

  const f32x4 fzero = {0.f, 0.f, 0.f, 0.f};
  f32x4 acc[2][4];
  #pragma unroll
  for (int a = 0; a < 2; ++a)
    #pragma unroll
    for (int b = 0; b < 4; ++b) acc[a][b] = fzero;

  const short* ybase = Yg + (size_t)n * S_DIM * C_DIM;

  #pragma unroll 2
  for (int kk = 0; kk < 8; ++kk) {
    bf16x8 af[2];
    #pragma unroll
    for (int mf = 0; mf < 2; ++mf)
      af[mf] = *(const bf16x8*)(ybase + (size_t)(s0 + mf * 16 + l15) * C_DIM +
                                kk * 32 + l4 * 8);
    #pragma unroll
    for (int nf = 0; nf < 4; ++nf) {
      int o = wid * 64 + nf * 16 + l15;
      bf16x8 bfr = *(const bf16x8*)(Wpb + o * C_DIM + kk * 32 + l4 * 8);
      #pragma unroll
      for (int mf = 0; mf < 2; ++mf)
        acc[mf][nf] = __builtin_amdgcn_mfma_f32_16x16x32_bf16(af[mf], bfr, acc[mf][nf], 0, 0, 0);
    }
  }

  #pragma unroll
  for (int mf = 0; mf < 2; ++mf) {
    #pragma unroll
    for (int nf = 0; nf < 4; ++nf) {
      int o = wid * 64 + nf * 16 + l15;
      size_t idx = ((size_t)n * C_DIM + o) * (size_t)S_DIM + s0 + mf * 16 + l4 * 4;
      float4 xv = *(const float4*)(x + idx);
      float4 r;
      r.x = xv.x + acc[mf][nf][0];
      r.y = xv.y + acc[mf][nf][1];
      r.z = xv.z + acc[mf][nf][2];
      r.w = xv.w + acc[mf][nf][3];
      *(float4*)(out + idx) = r;
    }
  }
}

// ---------------------------------------------------------------------------
extern "C" void kernel_launch(void* const* d_in, const int* in_sizes, int n_in,
                              void* d_out, int out_size, void* d_ws, size_t ws_size,
                              hipStream_t stream) {
  const float* x   = (const float*)d_in[0];
  const float* Wth = (const float*)d_in[1];
  const float* Wph = (const float*)d_in[2];
  const float* Wpr = (const float*)d_in[3];
  float* out = (float*)d_out;

  short* q_ws  = (short*)d_ws;                              // 4 MB  [N,S,E] bf16
  short* k_ws  = q_ws + (size_t)4 * S_DIM * E_DIM;          // 4 MB  [N,S,E] bf16
  unsigned char* xb8_ws = (unsigned char*)(k_ws + (size_t)4 * S_DIM * E_DIM); // 4 MB [N,C,S] fp8
  short* y_ws  = (short*)(xb8_ws + (size_t)4 * C_DIM * S_DIM);  // 8 MB [N,S,C] bf16
  short* wb_ws = y_ws + (size_t)4 * S_DIM * C_DIM;          // 256 KB bf16 weights

  float qscale = 1.4426950408889634f / sqrtf(128.0f);       // log2(e)/sqrt(E)

  cast_w_kernel<<<128, 256, 0, stream>>>(Wth, Wph, Wpr, wb_ws);
  mix_kernel<<<512, 256, 0, stream>>>(x, wb_ws, q_ws, k_ws, xb8_ws, qscale);
  attn_kernel<<<512, 256, 0, stream>>>(q_ws, k_ws, xb8_ws, y_ws);
  proj_kernel<<<512, 256, 0, stream>>>(y_ws, wb_ws + 65536, x, out);
}

// Round 11
// 152.922 us; speedup vs baseline: 1.1347x; 1.1347x over previous
//
#include <hip/hip_runtime.h>
#include <cmath>

#define C_DIM 256
#define E_DIM 128
#define S_DIM 4096

typedef __bf16 bf16x8 __attribute__((ext_vector_type(8)));
typedef float  f32x4  __attribute__((ext_vector_type(4)));
typedef short  s16x8  __attribute__((ext_vector_type(8)));
typedef short  s16x4  __attribute__((ext_vector_type(4)));

__device__ __forceinline__ unsigned short f2bf(float f) {
  union { float f; unsigned u; } v; v.f = f;
  unsigned r = v.u + 0x7FFFu + ((v.u >> 16) & 1u);
  return (unsigned short)(r >> 16);
}
__device__ __forceinline__ unsigned short f2bf_tr(float f) {  // truncating
  union { float f; unsigned u; } v; v.f = f;
  return (unsigned short)(v.u >> 16);
}
__device__ __forceinline__ float bf2f(unsigned short b) {
  union { unsigned u; float f; } v; v.u = ((unsigned)b) << 16;
  return v.f;
}
__device__ __forceinline__ bf16x8 as_bf(s16x8 v) {
  union { s16x8 s; bf16x8 b; } u; u.s = v; return u.b;
}
// 16B register-union bitcasts (compile to nothing)
__device__ __forceinline__ bf16x8 f2b8(f32x4 v) { union { f32x4 f; bf16x8 b; } u; u.f = v; return u.b; }
__device__ __forceinline__ f32x4 b2f8(bf16x8 v) { union { bf16x8 b; f32x4 f; } u; u.b = v; return u.f; }
__device__ __forceinline__ f32x4 s2f8(s16x8 v)  { union { s16x8 s; f32x4 f; } u; u.s = v; return u.f; }
__device__ __forceinline__ s16x8 f2s8(f32x4 v)  { union { f32x4 f; s16x8 s; } u; u.f = v; return u.s; }

// ---------------------------------------------------------------------------
// Kernel 0: cast weights fp32 -> bf16. [Wth 32768][Wph 32768][Wproj 65536].
// ---------------------------------------------------------------------------
__global__ __launch_bounds__(256) void cast_w_kernel(
    const float* __restrict__ Wth, const float* __restrict__ Wph,
    const float* __restrict__ Wpr, short* __restrict__ Wb) {
  int t = blockIdx.x * 256 + threadIdx.x;
  int i = t * 4;
  const float* src; int j;
  if (i < 32768)      { src = Wth; j = i; }
  else if (i < 65536) { src = Wph; j = i - 32768; }
  else                { src = Wpr; j = i - 65536; }
  float4 v = *(const float4*)(src + j);
  s16x4 o;
  o[0] = (short)f2bf(v.x); o[1] = (short)f2bf(v.y);
  o[2] = (short)f2bf(v.z); o[3] = (short)f2bf(v.w);
  *(s16x4*)(Wb + i) = o;
}

// ---------------------------------------------------------------------------
// Kernel 1 (MFMA): Q[s,e] = qscale * sum_c Wth[e,c] x[c,s]; K likewise.
// Emits bf16 x. Softmax log2-scale folded into Q. grid 512.
// ---------------------------------------------------------------------------
__global__ __launch_bounds__(256) void mix_kernel(
    const float* __restrict__ x, const short* __restrict__ Wb,
    short* __restrict__ Qg, short* __restrict__ Kg, short* __restrict__ Xb,
    float qscale) {
  __shared__ short lxT[32 * C_DIM];   // [s][c] bf16, swizzled, 16 KB
  int bid = blockIdx.x;
  int n = bid >> 7, s0 = (bid & 127) * 32;
  int tid = threadIdx.x;
  int wid = tid >> 6, lane = tid & 63, l15 = lane & 15, l4 = lane >> 4;

  { // stage x^T tile + emit Xb
    int cp = tid >> 1, su = tid & 1;
    const float* r0 = x + ((size_t)n * C_DIM + 2 * cp) * S_DIM + s0 + su * 16;
    const float* r1 = r0 + S_DIM;
    float a0[16], a1[16];
    #pragma unroll
    for (int j = 0; j < 4; ++j) {
      *(float4*)(a0 + 4 * j) = *(const float4*)(r0 + 4 * j);
      *(float4*)(a1 + 4 * j) = *(const float4*)(r1 + 4 * j);
    }
    short b0[16], b1[16];
    #pragma unroll
    for (int j = 0; j < 16; ++j) { b0[j] = (short)f2bf(a0[j]); b1[j] = (short)f2bf(a1[j]); }
    short* xb0 = Xb + ((size_t)n * C_DIM + 2 * cp) * S_DIM + s0 + su * 16;
    *(s16x8*)(xb0)             = *(s16x8*)(b0);
    *(s16x8*)(xb0 + 8)         = *(s16x8*)(b0 + 8);
    *(s16x8*)(xb0 + S_DIM)     = *(s16x8*)(b1);
    *(s16x8*)(xb0 + S_DIM + 8) = *(s16x8*)(b1 + 8);
    #pragma unroll
    for (int j = 0; j < 16; ++j) {
      int s = su * 16 + j;
      unsigned d = (unsigned)(unsigned short)b0[j] |
                   ((unsigned)(unsigned short)b1[j] << 16);
      *(unsigned*)((char*)lxT + s * 512 + ((4 * cp) ^ ((s & 7) << 4))) = d;
    }
  }
  __syncthreads();

  const short* Wq = Wb;
  const short* Wk = Wb + 32768;
  const f32x4 fzero = {0.f, 0.f, 0.f, 0.f};
  f32x4 accQ[2][2], accK[2][2];
  #pragma unroll
  for (int a = 0; a < 2; ++a)
    #pragma unroll
    for (int b = 0; b < 2; ++b) { accQ[a][b] = fzero; accK[a][b] = fzero; }

  #pragma unroll 2
  for (int kk = 0; kk < 8; ++kk) {
    bf16x8 bfr[2];
    #pragma unroll
    for (int nf = 0; nf < 2; ++nf) {
      int s = nf * 16 + l15;
      bfr[nf] = *(const bf16x8*)((char*)lxT + s * 512 +
                                 ((kk * 64 + l4 * 16) ^ ((s & 7) << 4)));
    }
    #pragma unroll
    for (int mf = 0; mf < 2; ++mf) {
      int e = wid * 32 + mf * 16 + l15;
      bf16x8 aq = *(const bf16x8*)(Wq + e * C_DIM + kk * 32 + l4 * 8);
      bf16x8 ak = *(const bf16x8*)(Wk + e * C_DIM + kk * 32 + l4 * 8);
      #pragma unroll
      for (int nf = 0; nf < 2; ++nf) {
        accQ[mf][nf] = __builtin_amdgcn_mfma_f32_16x16x32_bf16(aq, bfr[nf], accQ[mf][nf], 0, 0, 0);
        accK[mf][nf] = __builtin_amdgcn_mfma_f32_16x16x32_bf16(ak, bfr[nf], accK[mf][nf], 0, 0, 0);
      }
    }
  }

  #pragma unroll
  for (int mf = 0; mf < 2; ++mf) {
    #pragma unroll
    for (int nf = 0; nf < 2; ++nf) {
      int e = wid * 32 + mf * 16 + l4 * 4;
      int s = s0 + nf * 16 + l15;
      s16x4 pq, pk;
      #pragma unroll
      for (int r = 0; r < 4; ++r) {
        pq[r] = (short)f2bf(accQ[mf][nf][r] * qscale);
        pk[r] = (short)f2bf(accK[mf][nf][r]);
      }
      *(s16x4*)(Qg + ((size_t)n * S_DIM + s) * E_DIM + e) = pq;
      *(s16x4*)(Kg + ((size_t)n * S_DIM + s) * E_DIM + e) = pk;
    }
  }
}

// ---------------------------------------------------------------------------
// Kernel 2: flash attention, 128-q blocks x t-half (partial outputs).
// Grid 256 = 4n x 2 t-half x 32 q-tiles, 1 block/CU, 8 waves.
// QKT waves 0-3 = (t-half x q-half), 32 MFMA; PV waves 4-7 = c-quarter x all
// 128 q, 64 MFMA + K staging. 32 windows of 64 t, ONE RAW barrier each
// (r9's exact parity/hazard schedule). Register unions identical to r9:
//   RA[16] = QKT qf | PV vpreE(0..7)/vpreO(8..15)
//   RB[8]  = QKT sc(8 accumulators) | PV kpreE(0..3)/kpreO(4..7)
// acc[8][4] -> 128 AGPR. Writes partial bf16 numerator + f32 denominator.
// ---------------------------------------------------------------------------

#define QF(qs, ec) f2b8(RA[(qs) * 4 + (ec)])

#define QKT_BODY(B)                                                           \
  {                                                                           \
    const char* kb = lK + (B) * 16384;                                        \
    char* pw = lP + (B) * 16384;                                              \
    _Pragma("unroll")                                                         \
    for (int z = 0; z < 8; ++z) RB[z] = fzero;                                \
    int trow0 = th2 * 32 + l15;                                               \
    int trow1 = trow0 + 16;                                                   \
    int swz0 = (trow0 & 7) << 4, swz1 = (trow1 & 7) << 4;                     \
    __builtin_amdgcn_s_setprio(1);                                            \
    _Pragma("unroll")                                                         \
    for (int ec = 0; ec < 4; ++ec) {                                          \
      bf16x8 kf0 = *(const bf16x8*)(kb + trow0 * 256 + ((ec * 64 + l4 * 16) ^ swz0)); \
      bf16x8 kf1 = *(const bf16x8*)(kb + trow1 * 256 + ((ec * 64 + l4 * 16) ^ swz1)); \
      _Pragma("unroll")                                                       \
      for (int qs = 0; qs < 4; ++qs) {                                        \
        RB[qs]     = __builtin_amdgcn_mfma_f32_16x16x32_bf16(kf0, QF(qs, ec), RB[qs], 0, 0, 0);     \
        RB[4 + qs] = __builtin_amdgcn_mfma_f32_16x16x32_bf16(kf1, QF(qs, ec), RB[4 + qs], 0, 0, 0); \
      }                                                                       \
    }                                                                         \
    __builtin_amdgcn_s_setprio(0);                                            \
    _Pragma("unroll")                                                         \
    for (int tb = 0; tb < 2; ++tb) {                                          \
      int tbyte = th2 * 64 + tb * 32 + l4 * 8;                                \
      _Pragma("unroll")                                                       \
      for (int qs = 0; qs < 4; ++qs) {                                        \
        f32x4 sv = RB[tb * 4 + qs];                                           \
        float p0 = __builtin_amdgcn_exp2f(sv[0]);                             \
        float p1 = __builtin_amdgcn_exp2f(sv[1]);                             \
        float p2 = __builtin_amdgcn_exp2f(sv[2]);                             \
        float p3 = __builtin_amdgcn_exp2f(sv[3]);                             \
        lsum[qs] += (p0 + p1) + (p2 + p3);                                    \
        uint2 dd;                                                             \
        dd.x = (unsigned)f2bf_tr(p0) | ((unsigned)f2bf_tr(p1) << 16);         \
        dd.y = (unsigned)f2bf_tr(p2) | ((unsigned)f2bf_tr(p3) << 16);         \
        int q = qh * 64 + qs * 16 + l15;                                      \
        *(uint2*)(pw + q * 128 + (tbyte ^ ((q & 7) << 4))) = dd;              \
      }                                                                       \
    }                                                                         \
  }

#define PV_VISSUE(OFF, TI)                                                    \
  _Pragma("unroll")                                                           \
  for (int kk = 0; kk < 2; ++kk)                                              \
    _Pragma("unroll")                                                         \
    for (int ct = 0; ct < 4; ++ct)                                            \
      RA[(OFF) + kk * 4 + ct] = s2f8(*(const s16x8*)(                         \
          Vb2 + (size_t)(cq * 64 + ct * 16 + l15) * S_DIM + (TI) * 64 + kk * 32 + l4 * 8));

#define PV_KCOMMIT(OFF, B)                                                    \
  {                                                                           \
    char* kw = lK + (B) * 16384;                                              \
    _Pragma("unroll")                                                         \
    for (int jj = 0; jj < 4; ++jj) {                                          \
      int r = kr + 16 * jj;                                                   \
      *(s16x8*)(kw + r * 256 + ((kc * 16) ^ ((r & 7) << 4))) = f2s8(RB[(OFF) + jj]); \
    }                                                                         \
  }

#define PV_KLOAD(OFF, TI)                                                     \
  _Pragma("unroll")                                                           \
  for (int jj = 0; jj < 4; ++jj)                                              \
    RB[(OFF) + jj] = s2f8(*(const s16x8*)(                                    \
        Kb2 + (size_t)((TI) * 64 + kr + 16 * jj) * E_DIM + kc * 8));

#define PV_MFMA(OFF, PBUF)                                                    \
  {                                                                           \
    const char* pr = lP + (PBUF) * 16384;                                     \
    _Pragma("unroll")                                                         \
    for (int kk = 0; kk < 2; ++kk) {                                          \
      _Pragma("unroll")                                                       \
      for (int qh2 = 0; qh2 < 2; ++qh2) {                                     \
        bf16x8 pf[4];                                                         \
        _Pragma("unroll")                                                     \
        for (int qs = 0; qs < 4; ++qs) {                                      \
          int q = qh2 * 64 + qs * 16 + l15;                                   \
          pf[qs] = *(const bf16x8*)(pr + q * 128 + ((kk * 64 + l4 * 16) ^ ((q & 7) << 4))); \
        }                                                                     \
        __builtin_amdgcn_s_setprio(1);                                        \
        _Pragma("unroll")                                                     \
        for (int ct = 0; ct < 4; ++ct) {                                      \
          bf16x8 vf = as_bf(f2s8(RA[(OFF) + kk * 4 + ct]));                   \
          _Pragma("unroll")                                                   \
          for (int qs = 0; qs < 4; ++qs)                                      \
            acc[qh2 * 4 + qs][ct] = __builtin_amdgcn_mfma_f32_16x16x32_bf16(  \
                pf[qs], vf, acc[qh2 * 4 + qs][ct], 0, 0, 0);                  \
        }                                                                     \
        __builtin_amdgcn_s_setprio(0);                                        \
      }                                                                       \
    }                                                                         \
  }

#define RAW_BARRIER()                                                         \
  asm volatile("s_waitcnt lgkmcnt(0)" ::: "memory");                          \
  __builtin_amdgcn_s_barrier();

__global__ __launch_bounds__(512, 2) void attn_kernel(
    const short* __restrict__ Qg, const short* __restrict__ Kg,
    const short* __restrict__ Xb, short* __restrict__ Yn,
    float* __restrict__ Ls) {
  // one carved smem block: lK dbuf 32 KB | lP dbuf 32 KB | lsred 1 KB.
  // Epilogue reuses the first 64 KB as yst [128 q][256 c] bf16 swizzled.
  __shared__ __align__(16) char smem[66560];
  char* lK = smem;
  char* lP = smem + 32768;
  float* lsred = (float*)(smem + 65536);   // [2 t-half][128 q]

  int bid = blockIdx.x;
  int xcd = bid & 7;            // dispatch round-robins XCDs
  int n   = xcd >> 1;           // batch pinned to an XCD pair
  int th  = xcd & 1;            // t-half pinned within the pair
  int s0  = (bid >> 3) * 128;   // q-tile (32 tiles of 128)
  int tbase = th * 2048;

  int tid = threadIdx.x;
  int wid = tid >> 6, lane = tid & 63;
  int l15 = lane & 15, l4 = lane >> 4;

  const short* Kb2 = Kg + (size_t)n * S_DIM * E_DIM + (size_t)tbase * E_DIM;
  const short* Vb2 = Xb + (size_t)n * (size_t)C_DIM * S_DIM + tbase;

  const f32x4 fzero = {0.f, 0.f, 0.f, 0.f};

  // ------------- role-unioned register file (static indices only) -------
  f32x4 RA[16];             // QKT: qf[qs][ec] | PV: vpreE(0..7)/vpreO(8..15)
  f32x4 RB[8];              // QKT: sc(0..7)   | PV: kpreE(0..3)/kpreO(4..7)
  float lsum[4];            // QKT only
  f32x4 acc[8][4];          // PV only (128 AGPR)

  int th2 = wid & 1;        // QKT: t-half within window (32 t)
  int qh  = wid >> 1;       // QKT: q-half (64 q)
  int cq  = wid - 4;        // PV:  c-quarter
  int idx = tid & 255;
  int kr = idx >> 4, kc = idx & 15;   // K staging (PV waves, 256 threads)

  if (wid < 4) {
    #pragma unroll
    for (int qs = 0; qs < 4; ++qs) {
      const short* qp = Qg + ((size_t)n * S_DIM + s0 + qh * 64 + qs * 16 + l15) * E_DIM + l4 * 8;
      #pragma unroll
      for (int ec = 0; ec < 4; ++ec) RA[qs * 4 + ec] = b2f8(*(const bf16x8*)(qp + ec * 32));
    }
    #pragma unroll
    for (int j = 0; j < 4; ++j) lsum[j] = 0.f;
  } else {
    #pragma unroll
    for (int a = 0; a < 8; ++a)
      #pragma unroll
      for (int b = 0; b < 4; ++b) acc[a][b] = fzero;
    // stage K tile 0 into lK buf0 (via RB[0..3], dead after commit)
    PV_KLOAD(0, 0);
    PV_KCOMMIT(0, 0);
    // prefetch K tile 1 -> kpreO(RB[4..7]); V tile 0 -> vpreE(RA[0..7])
    PV_KLOAD(4, 1);
    PV_VISSUE(0, 0);
  }
  RAW_BARRIER();

  // ------------- main: 16 iterations x 2 windows = 32 windows -----------
  for (int j = 0; j < 16; ++j) {
    int i0 = 2 * j;
    // ---- window i0 (even): QKT on lK buf0 -> lP buf0
    if (wid < 4) {
      QKT_BODY(0);
    } else {
      if (j > 0)  PV_VISSUE(0, i0);            // vpreE <- V tile i0 (cons. i0+1)
      PV_KCOMMIT(4, 1);                         // kpreO -> K buf1 (tile i0+1)
      if (j > 0)  PV_MFMA(8, 1);                // PV tile i0-1 (vpreO, P buf1)
      if (j < 15) PV_KLOAD(0, i0 + 2);          // kpreE <- K tile i0+2
    }
    RAW_BARRIER();
    // ---- window i0+1 (odd): QKT on lK buf1 -> lP buf1
    if (wid < 4) {
      QKT_BODY(1);
    } else {
      PV_VISSUE(8, i0 + 1);                     // vpreO <- V tile i0+1 (cons. i0+2)
      if (j < 15) PV_KCOMMIT(0, 0);             // kpreE -> K buf0 (tile i0+2)
      PV_MFMA(0, 0);                            // PV tile i0 (vpreE, P buf0)
      if (j < 15) PV_KLOAD(4, i0 + 3);          // kpreO <- K tile i0+3
    }
    RAW_BARRIER();
  }
  // final window 32: PV on tile 31 (P in buf1, V in vpreO)
  if (wid >= 4) {
    PV_MFMA(8, 1);
  }

  // ---------------- epilogue: partial denom + partial numerator ----------
  if (wid < 4) {
    #pragma unroll
    for (int qs = 0; qs < 4; ++qs) {
      float v = lsum[qs];
      v += __shfl_xor(v, 16);
      v += __shfl_xor(v, 32);
      if (lane < 16) lsred[th2 * 128 + qh * 64 + qs * 16 + l15] = v;
    }
  }
  __syncthreads();

  char* yst = smem;   // reuse 64 KB as [128 q][256 c] bf16, swizzled
  if (wid >= 4) {
    #pragma unroll
    for (int qg = 0; qg < 8; ++qg) {
      #pragma unroll
      for (int r = 0; r < 4; ++r) {
        int q = qg * 16 + l4 * 4 + r;
        #pragma unroll
        for (int ct = 0; ct < 4; ++ct) {
          int c = cq * 64 + ct * 16 + l15;
          *(unsigned short*)(yst + q * 512 + ((c * 2) ^ ((q & 7) << 4))) =
              f2bf_tr(acc[qg][ct][r]);
        }
      }
    }
  }
  __syncthreads();

  size_t obase = ((size_t)th * 4 + n) * S_DIM;
  #pragma unroll
  for (int it = 0; it < 8; ++it) {
    int ii = it * 512 + tid;
    int rr = ii >> 5, ch = ii & 31;
    s16x8 v = *(const s16x8*)(yst + rr * 512 + ((ch * 16) ^ ((rr & 7) << 4)));
    *(s16x8*)(Yn + (obase + s0 + rr) * C_DIM + ch * 8) = v;
  }
  if (tid < 128) {
    Ls[obase + s0 + tid] = lsred[tid] + lsred[128 + tid];
  }
}

// ---------------------------------------------------------------------------
// Kernel 3 (MFMA, zero LDS): out[o,s] = x[o,s] + sum_c Wp[o,c] *
//   ((yn0[s,c]+yn1[s,c]) / (l0[s]+l1[s]))    -- combines the t-half partials
// ---------------------------------------------------------------------------
__global__ __launch_bounds__(256) void proj_kernel(
    const short* __restrict__ Yn, const float* __restrict__ Ls,
    const short* __restrict__ Wpb, const float* __restrict__ x,
    float* __restrict__ out) {
  int bid = blockIdx.x;
  int n = bid >> 7, s0 = (bid & 127) * 32;
  int tid = threadIdx.x;
  int wid = tid >> 6, lane = tid & 63, l15 = lane & 15, l4 = lane >> 4;

  const short* y0 = Yn + (size_t)n * S_DIM * C_DIM;
  const short* y1 = y0 + (size_t)4 * S_DIM * C_DIM;
  const float* l0 = Ls + (size_t)n * S_DIM;
  const float* l1 = l0 + (size_t)4 * S_DIM;

  int srow[2]; float rl[2];
  #pragma unroll
  for (int mf = 0; mf < 2; ++mf) {
    int s = s0 + mf * 16 + l15;
    srow[mf] = s;
    rl[mf] = 1.0f / (l0[s] + l1[s]);
  }

  const f32x4 fzero = {0.f, 0.f, 0.f, 0.f};
  f32x4 acc[2][4];
  #pragma unroll
  for (int a = 0; a < 2; ++a)
    #pragma unroll
    for (int b = 0; b < 4; ++b) acc[a][b] = fzero;

  #pragma unroll 2
  for (int kk = 0; kk < 8; ++kk) {
    bf16x8 af[2];
    #pragma unroll
    for (int mf = 0; mf < 2; ++mf) {
      size_t off = (size_t)srow[mf] * C_DIM + kk * 32 + l4 * 8;
      s16x8 a0 = *(const s16x8*)(y0 + off);
      s16x8 a1 = *(const s16x8*)(y1 + off);
      s16x8 t;
      #pragma unroll
      for (int jj = 0; jj < 8; ++jj) {
        float f = (bf2f((unsigned short)a0[jj]) + bf2f((unsigned short)a1[jj])) * rl[mf];
        t[jj] = (short)f2bf(f);
      }
      af[mf] = as_bf(t);
    }
    #pragma unroll
    for (int nf = 0; nf < 4; ++nf) {
      int o = wid * 64 + nf * 16 + l15;
      bf16x8 bfr = *(const bf16x8*)(Wpb + o * C_DIM + kk * 32 + l4 * 8);
      #pragma unroll
      for (int mf = 0; mf < 2; ++mf)
        acc[mf][nf] = __builtin_amdgcn_mfma_f32_16x16x32_bf16(af[mf], bfr, acc[mf][nf], 0, 0, 0);
    }
  }

  #pragma unroll
  for (int mf = 0; mf < 2; ++mf) {
    #pragma unroll
    for (int nf = 0; nf < 4; ++nf) {
      int o = wid * 64 + nf * 16 + l15;
      size_t idx = ((size_t)n * C_DIM + o) * (size_t)S_DIM + s0 + mf * 16 + l4 * 4;
      float4 xv = *(const float4*)(x + idx);
      float4 r;
      r.x = xv.x + acc[mf][nf][0];
      r.y = xv.y + acc[mf][nf][1];
      r.z = xv.z + acc[mf][nf][2];
      r.w = xv.w + acc[mf][nf][3];
      *(float4*)(out + idx) = r;
    }
  }
}

// ---------------------------------------------------------------------------
extern "C" void kernel_launch(void* const* d_in, const int* in_sizes, int n_in,
                              void* d_out, int out_size, void* d_ws, size_t ws_size,
                              hipStream_t stream) {
  const float* x   = (const float*)d_in[0];
  const float* Wth = (const float*)d_in[1];
  const float* Wph = (const float*)d_in[2];
  const float* Wpr = (const float*)d_in[3];
  float* out = (float*)d_out;

  short* q_ws  = (short*)d_ws;                              // 4 MB  [N,S,E]
  short* k_ws  = q_ws  + (size_t)4 * S_DIM * E_DIM;         // 4 MB  [N,S,E]
  short* xb_ws = k_ws  + (size_t)4 * S_DIM * E_DIM;         // 8 MB  [N,C,S]
  short* yn_ws = xb_ws + (size_t)4 * C_DIM * S_DIM;         // 16 MB [2,N,S,C] bf16 partials
  short* wb_ws = yn_ws + (size_t)2 * 4 * S_DIM * C_DIM;     // 256 KB bf16 weights
  float* ls_ws = (float*)(wb_ws + 131072);                  // 128 KB [2,N,S] f32 denoms

  float qscale = 1.4426950408889634f / sqrtf(128.0f);       // log2(e)/sqrt(E)

  cast_w_kernel<<<128, 256, 0, stream>>>(Wth, Wph, Wpr, wb_ws);
  mix_kernel<<<512, 256, 0, stream>>>(x, wb_ws, q_ws, k_ws, xb_ws, qscale);
  attn_kernel<<<256, 512, 0, stream>>>(q_ws, k_ws, xb_ws, yn_ws, ls_ws);
  proj_kernel<<<512, 256, 0, stream>>>(yn_ws, ls_ws, wb_ws + 65536, x, out);
}

// Round 12
// 138.468 us; speedup vs baseline: 1.2531x; 1.1044x over previous
//
#include <hip/hip_runtime.h>
#include <cmath>

#define C_DIM 256
#define E_DIM 128
#define S_DIM 4096

typedef __bf16 bf16x8 __attribute__((ext_vector_type(8)));
typedef float  f32x4  __attribute__((ext_vector_type(4)));
typedef short  s16x8  __attribute__((ext_vector_type(8)));
typedef short  s16x4  __attribute__((ext_vector_type(4)));

__device__ __forceinline__ unsigned short f2bf(float f) {
  union { float f; unsigned u; } v; v.f = f;
  unsigned r = v.u + 0x7FFFu + ((v.u >> 16) & 1u);
  return (unsigned short)(r >> 16);
}
__device__ __forceinline__ unsigned short f2bf_tr(float f) {  // truncating
  union { float f; unsigned u; } v; v.f = f;
  return (unsigned short)(v.u >> 16);
}
__device__ __forceinline__ bf16x8 as_bf(s16x8 v) {
  union { s16x8 s; bf16x8 b; } u; u.s = v; return u.b;
}
// 16B register-union bitcasts (compile to nothing)
__device__ __forceinline__ bf16x8 f2b8(f32x4 v) { union { f32x4 f; bf16x8 b; } u; u.f = v; return u.b; }
__device__ __forceinline__ f32x4 b2f8(bf16x8 v) { union { bf16x8 b; f32x4 f; } u; u.b = v; return u.f; }
__device__ __forceinline__ f32x4 s2f8(s16x8 v)  { union { s16x8 s; f32x4 f; } u; u.s = v; return u.f; }
__device__ __forceinline__ s16x8 f2s8(f32x4 v)  { union { f32x4 f; s16x8 s; } u; u.f = v; return u.s; }

// ---------------------------------------------------------------------------
// Kernel 0: cast weights fp32 -> bf16. [Wth 32768][Wph 32768][Wproj 65536].
// ---------------------------------------------------------------------------
__global__ __launch_bounds__(256) void cast_w_kernel(
    const float* __restrict__ Wth, const float* __restrict__ Wph,
    const float* __restrict__ Wpr, short* __restrict__ Wb) {
  int t = blockIdx.x * 256 + threadIdx.x;
  int i = t * 4;
  const float* src; int j;
  if (i < 32768)      { src = Wth; j = i; }
  else if (i < 65536) { src = Wph; j = i - 32768; }
  else                { src = Wpr; j = i - 65536; }
  float4 v = *(const float4*)(src + j);
  s16x4 o;
  o[0] = (short)f2bf(v.x); o[1] = (short)f2bf(v.y);
  o[2] = (short)f2bf(v.z); o[3] = (short)f2bf(v.w);
  *(s16x4*)(Wb + i) = o;
}

// ---------------------------------------------------------------------------
// Kernel 1 (MFMA): Q[s,e] = qscale * sum_c Wth[e,c] x[c,s]; K likewise.
// Emits bf16 x. Softmax log2-scale folded into Q. grid 512.
// ---------------------------------------------------------------------------
__global__ __launch_bounds__(256) void mix_kernel(
    const float* __restrict__ x, const short* __restrict__ Wb,
    short* __restrict__ Qg, short* __restrict__ Kg, short* __restrict__ Xb,
    float qscale) {
  __shared__ short lxT[32 * C_DIM];   // [s][c] bf16, swizzled, 16 KB
  int bid = blockIdx.x;
  int n = bid >> 7, s0 = (bid & 127) * 32;
  int tid = threadIdx.x;
  int wid = tid >> 6, lane = tid & 63, l15 = lane & 15, l4 = lane >> 4;

  { // stage x^T tile + emit Xb
    int cp = tid >> 1, su = tid & 1;
    const float* r0 = x + ((size_t)n * C_DIM + 2 * cp) * S_DIM + s0 + su * 16;
    const float* r1 = r0 + S_DIM;
    float a0[16], a1[16];
    #pragma unroll
    for (int j = 0; j < 4; ++j) {
      *(float4*)(a0 + 4 * j) = *(const float4*)(r0 + 4 * j);
      *(float4*)(a1 + 4 * j) = *(const float4*)(r1 + 4 * j);
    }
    short b0[16], b1[16];
    #pragma unroll
    for (int j = 0; j < 16; ++j) { b0[j] = (short)f2bf(a0[j]); b1[j] = (short)f2bf(a1[j]); }
    short* xb0 = Xb + ((size_t)n * C_DIM + 2 * cp) * S_DIM + s0 + su * 16;
    *(s16x8*)(xb0)             = *(s16x8*)(b0);
    *(s16x8*)(xb0 + 8)         = *(s16x8*)(b0 + 8);
    *(s16x8*)(xb0 + S_DIM)     = *(s16x8*)(b1);
    *(s16x8*)(xb0 + S_DIM + 8) = *(s16x8*)(b1 + 8);
    #pragma unroll
    for (int j = 0; j < 16; ++j) {
      int s = su * 16 + j;
      unsigned d = (unsigned)(unsigned short)b0[j] |
                   ((unsigned)(unsigned short)b1[j] << 16);
      *(unsigned*)((char*)lxT + s * 512 + ((4 * cp) ^ ((s & 7) << 4))) = d;
    }
  }
  __syncthreads();

  const short* Wq = Wb;
  const short* Wk = Wb + 32768;
  const f32x4 fzero = {0.f, 0.f, 0.f, 0.f};
  f32x4 accQ[2][2], accK[2][2];
  #pragma unroll
  for (int a = 0; a < 2; ++a)
    #pragma unroll
    for (int b = 0; b < 2; ++b) { accQ[a][b] = fzero; accK[a][b] = fzero; }

  #pragma unroll 2
  for (int kk = 0; kk < 8; ++kk) {
    bf16x8 bfr[2];
    #pragma unroll
    for (int nf = 0; nf < 2; ++nf) {
      int s = nf * 16 + l15;
      bfr[nf] = *(const bf16x8*)((char*)lxT + s * 512 +
                                 ((kk * 64 + l4 * 16) ^ ((s & 7) << 4)));
    }
    #pragma unroll
    for (int mf = 0; mf < 2; ++mf) {
      int e = wid * 32 + mf * 16 + l15;
      bf16x8 aq = *(const bf16x8*)(Wq + e * C_DIM + kk * 32 + l4 * 8);
      bf16x8 ak = *(const bf16x8*)(Wk + e * C_DIM + kk * 32 + l4 * 8);
      #pragma unroll
      for (int nf = 0; nf < 2; ++nf) {
        accQ[mf][nf] = __builtin_amdgcn_mfma_f32_16x16x32_bf16(aq, bfr[nf], accQ[mf][nf], 0, 0, 0);
        accK[mf][nf] = __builtin_amdgcn_mfma_f32_16x16x32_bf16(ak, bfr[nf], accK[mf][nf], 0, 0, 0);
      }
    }
  }

  #pragma unroll
  for (int mf = 0; mf < 2; ++mf) {
    #pragma unroll
    for (int nf = 0; nf < 2; ++nf) {
      int e = wid * 32 + mf * 16 + l4 * 4;
      int s = s0 + nf * 16 + l15;
      s16x4 pq, pk;
      #pragma unroll
      for (int r = 0; r < 4; ++r) {
        pq[r] = (short)f2bf(accQ[mf][nf][r] * qscale);
        pk[r] = (short)f2bf(accK[mf][nf][r]);
      }
      *(s16x4*)(Qg + ((size_t)n * S_DIM + s) * E_DIM + e) = pq;
      *(s16x4*)(Kg + ((size_t)n * S_DIM + s) * E_DIM + e) = pk;
    }
  }
}

// ---------------------------------------------------------------------------
// Kernel 2: flash attention, r9 schedule with K-LDS ELIMINATED.
// QKT waves (0-3) load their own K fragments straight from global (L2),
// double-buffered in registers (RB), issued ~2 windows ahead; PV waves (4-7)
// are pure V-issue + PV-MFMA. LDS holds only P (dbuf 16 KB). RAW lgkm-only
// barriers; swapped QK^T; setprio on MFMA clusters; grid 256, XCD-pinned.
// Register unions (static indices only):
//   RA[16] = QKT qf[qs][ec]          | PV vpreE(0..7)/vpreO(8..15)
//   RB[8]  = QKT kfE(0..3)/kfO(4..7) | PV unused
// ---------------------------------------------------------------------------

#define QF(qs, ec) f2b8(RA[(qs) * 4 + (ec)])

#define KF_ISSUE(OFF, TI)                                                     \
  _Pragma("unroll")                                                           \
  for (int ec = 0; ec < 4; ++ec)                                              \
    RB[(OFF) + ec] = s2f8(*(const s16x8*)(                                    \
        Kb + (size_t)((TI) * 64 + tq * 16 + l15) * E_DIM + ec * 32 + l4 * 8));

#define QKT_BODY(B, KOFF)                                                     \
  {                                                                           \
    char* pw = lP + (B) * 8192;                                               \
    f32x4 sc[4] = {fzero, fzero, fzero, fzero};                               \
    __builtin_amdgcn_s_setprio(1);                                            \
    _Pragma("unroll")                                                         \
    for (int ec = 0; ec < 4; ++ec) {                                          \
      bf16x8 kf = f2b8(RB[(KOFF) + ec]);                                      \
      _Pragma("unroll")                                                       \
      for (int qs = 0; qs < 4; ++qs)  /* swapped: D[t][q] */                  \
        sc[qs] = __builtin_amdgcn_mfma_f32_16x16x32_bf16(kf, QF(qs, ec), sc[qs], 0, 0, 0); \
    }                                                                         \
    __builtin_amdgcn_s_setprio(0);                                            \
    int tb2 = tq * 32 + l4 * 8;                                               \
    _Pragma("unroll")                                                         \
    for (int qs = 0; qs < 4; ++qs) {                                          \
      float p0 = __builtin_amdgcn_exp2f(sc[qs][0]);                           \
      float p1 = __builtin_amdgcn_exp2f(sc[qs][1]);                           \
      float p2 = __builtin_amdgcn_exp2f(sc[qs][2]);                           \
      float p3 = __builtin_amdgcn_exp2f(sc[qs][3]);                           \
      lsum[qs] += (p0 + p1) + (p2 + p3);                                      \
      uint2 dd;                                                               \
      dd.x = (unsigned)f2bf_tr(p0) | ((unsigned)f2bf_tr(p1) << 16);           \
      dd.y = (unsigned)f2bf_tr(p2) | ((unsigned)f2bf_tr(p3) << 16);           \
      int q = qs * 16 + l15;                                                  \
      *(uint2*)(pw + q * 128 + (tb2 ^ ((q & 7) << 4))) = dd;                  \
    }                                                                         \
  }

#define PV_VISSUE(OFF, TI)                                                    \
  _Pragma("unroll")                                                           \
  for (int kk = 0; kk < 2; ++kk)                                              \
    _Pragma("unroll")                                                         \
    for (int ct = 0; ct < 4; ++ct)                                            \
      RA[(OFF) + kk * 4 + ct] = s2f8(*(const s16x8*)(                         \
          Vb + (size_t)(cq * 64 + ct * 16 + l15) * S_DIM + (TI) * 64 + kk * 32 + l4 * 8));

#define PV_MFMA(OFF, PBUF)                                                    \
  {                                                                           \
    const char* pr = lP + (PBUF) * 8192;                                      \
    _Pragma("unroll")                                                         \
    for (int kk = 0; kk < 2; ++kk) {                                          \
      bf16x8 pf[4];                                                           \
      _Pragma("unroll")                                                       \
      for (int qs = 0; qs < 4; ++qs) {                                        \
        int q = qs * 16 + l15;                                                \
        pf[qs] = *(const bf16x8*)(pr + q * 128 + ((kk * 64 + l4 * 16) ^ ((q & 7) << 4))); \
      }                                                                       \
      __builtin_amdgcn_s_setprio(1);                                          \
      _Pragma("unroll")                                                       \
      for (int ct = 0; ct < 4; ++ct) {                                        \
        bf16x8 vf = as_bf(f2s8(RA[(OFF) + kk * 4 + ct]));                     \
        _Pragma("unroll")                                                     \
        for (int qs = 0; qs < 4; ++qs)                                        \
          acc[qs][ct] = __builtin_amdgcn_mfma_f32_16x16x32_bf16(pf[qs], vf, acc[qs][ct], 0, 0, 0); \
      }                                                                       \
      __builtin_amdgcn_s_setprio(0);                                          \
    }                                                                         \
  }

#define RAW_BARRIER()                                                         \
  asm volatile("s_waitcnt lgkmcnt(0)" ::: "memory");                          \
  __builtin_amdgcn_s_barrier();

__global__ __launch_bounds__(512, 2) void attn_kernel(
    const short* __restrict__ Qg, const short* __restrict__ Kg,
    const short* __restrict__ Xb, short* __restrict__ Yg) {
  // smem: main loop lP dbuf [0,16K); epilogue yst [0,32K) + lsred [32K,33K)
  __shared__ __align__(16) char smem[33792];
  char* lP = smem;
  float* lsred = (float*)(smem + 32768);

  int bid = blockIdx.x;
  int xcd = bid & 7;            // dispatch round-robins XCDs
  int n   = xcd >> 1;           // batch pinned to an XCD pair
  int s0  = (((xcd & 1) << 5) + (bid >> 3)) * 64;

  int tid = threadIdx.x;
  int wid = tid >> 6, lane = tid & 63;
  int l15 = lane & 15, l4 = lane >> 4;

  const short* Kb = Kg + (size_t)n * S_DIM * E_DIM;
  const short* Vb = Xb + (size_t)n * (size_t)C_DIM * S_DIM;

  const f32x4 fzero = {0.f, 0.f, 0.f, 0.f};

  // ------------- role-unioned register file (static indices only) -------
  f32x4 RA[16];             // QKT: qf | PV: vpreE(0..7)/vpreO(8..15)
  f32x4 RB[8];              // QKT: kfE(0..3)/kfO(4..7) | PV: unused
  float lsum[4];            // QKT only
  f32x4 acc[4][4];          // PV only (64 AGPR)

  int tq = wid;             // QKT: t-quarter
  int cq = wid - 4;         // PV:  c-quarter

  if (wid < 4) {
    #pragma unroll
    for (int qs = 0; qs < 4; ++qs) {
      const short* qp = Qg + ((size_t)n * S_DIM + s0 + qs * 16 + l15) * E_DIM + l4 * 8;
      #pragma unroll
      for (int ec = 0; ec < 4; ++ec) RA[qs * 4 + ec] = b2f8(*(const bf16x8*)(qp + ec * 32));
    }
    #pragma unroll
    for (int j = 0; j < 4; ++j) lsum[j] = 0.f;
    KF_ISSUE(0, 0);           // kfE <- K window 0
    KF_ISSUE(4, 1);           // kfO <- K window 1
  } else {
    #pragma unroll
    for (int a = 0; a < 4; ++a)
      #pragma unroll
      for (int b = 0; b < 4; ++b) acc[a][b] = fzero;
    PV_VISSUE(0, 0);          // vpreE <- V tile 0 (consumed at window 1)
  }
  RAW_BARRIER();

  // ------------- main: 32 iterations x 2 windows, static buffers -----------
  for (int j = 0; j < 32; ++j) {
    int i0 = 2 * j;
    // ---- window i0 (even): QKT with kfE -> lP buf0
    if (wid < 4) {
      QKT_BODY(0, 0);
      if (j < 31) KF_ISSUE(0, i0 + 2);          // kfE <- K window i0+2
    } else {
      if (j > 0)  PV_VISSUE(0, i0);             // vpreE <- V tile i0 (cons. i0+1)
      if (j > 0)  PV_MFMA(8, 1);                // PV tile i0-1 (vpreO, P buf1)
    }
    RAW_BARRIER();
    // ---- window i0+1 (odd): QKT with kfO -> lP buf1
    if (wid < 4) {
      QKT_BODY(1, 4);
      if (j < 31) KF_ISSUE(4, i0 + 3);          // kfO <- K window i0+3
    } else {
      PV_VISSUE(8, i0 + 1);                     // vpreO <- V tile i0+1 (cons. i0+2)
      PV_MFMA(0, 0);                            // PV tile i0 (vpreE, P buf0)
    }
    RAW_BARRIER();
  }
  // final window 64: PV on tile 63 (P in buf1, V in vpreO)
  if (wid >= 4) {
    PV_MFMA(8, 1);
  }

  // ---------------- epilogue ----------------
  if (wid < 4) {
    #pragma unroll
    for (int qs = 0; qs < 4; ++qs) {
      float v = lsum[qs];
      v += __shfl_xor(v, 16);
      v += __shfl_xor(v, 32);
      if (lane < 16) lsred[tq * 64 + qs * 16 + l15] = v;
    }
  }
  __syncthreads();

  char* yst = smem;   // reuse 32 KB as [64 q][256 c] bf16, swizzled
  if (wid >= 4) {
    #pragma unroll
    for (int qs = 0; qs < 4; ++qs) {
      #pragma unroll
      for (int r = 0; r < 4; ++r) {
        int q = qs * 16 + l4 * 4 + r;
        float tot = lsred[q] + lsred[64 + q] + lsred[128 + q] + lsred[192 + q];
        float rl = 1.0f / tot;
        #pragma unroll
        for (int ct = 0; ct < 4; ++ct) {
          int c = cq * 64 + ct * 16 + l15;
          *(unsigned short*)(yst + q * 512 + ((c * 2) ^ ((q & 7) << 4))) =
              f2bf_tr(acc[qs][ct][r] * rl);
        }
      }
    }
  }
  __syncthreads();

  int rr = tid >> 3, chb = tid & 7;
  #pragma unroll
  for (int it = 0; it < 4; ++it) {
    int ch = chb + 8 * it;
    s16x8 v = *(const s16x8*)(yst + rr * 512 + ((ch * 16) ^ ((rr & 7) << 4)));
    *(s16x8*)(Yg + ((size_t)n * S_DIM + s0 + rr) * C_DIM + ch * 8) = v;
  }
}

// ---------------------------------------------------------------------------
// Kernel 3 (MFMA, zero LDS): out[o,s] = x[o,s] + sum_c Wp[o,c] y[s,c]
// ---------------------------------------------------------------------------
__global__ __launch_bounds__(256) void proj_kernel(
    const short* __restrict__ Yg, const short* __restrict__ Wpb,
    const float* __restrict__ x, float* __restrict__ out) {
  int bid = blockIdx.x;
  int n = bid >> 7, s0 = (bid & 127) * 32;
  int tid = threadIdx.x;
  int wid = tid >> 6, lane = tid & 63, l15 = lane & 15, l4 = lane >> 4;

  const f32x4 fzero = {0.f, 0.f, 0.f, 0.f};
  f32x4 acc[2][4];
  #pragma unroll
  for (int a = 0; a < 2; ++a)
    #pragma unroll
    for (int b = 0; b < 4; ++b) acc[a][b] = fzero;

  const short* ybase = Yg + (size_t)n * S_DIM * C_DIM;

  #pragma unroll 2
  for (int kk = 0; kk < 8; ++kk) {
    bf16x8 af[2];
    #pragma unroll
    for (int mf = 0; mf < 2; ++mf)
      af[mf] = *(const bf16x8*)(ybase + (size_t)(s0 + mf * 16 + l15) * C_DIM +
                                kk * 32 + l4 * 8);
    #pragma unroll
    for (int nf = 0; nf < 4; ++nf) {
      int o = wid * 64 + nf * 16 + l15;
      bf16x8 bfr = *(const bf16x8*)(Wpb + o * C_DIM + kk * 32 + l4 * 8);
      #pragma unroll
      for (int mf = 0; mf < 2; ++mf)
        acc[mf][nf] = __builtin_amdgcn_mfma_f32_16x16x32_bf16(af[mf], bfr, acc[mf][nf], 0, 0, 0);
    }
  }

  #pragma unroll
  for (int mf = 0; mf < 2; ++mf) {
    #pragma unroll
    for (int nf = 0; nf < 4; ++nf) {
      int o = wid * 64 + nf * 16 + l15;
      size_t idx = ((size_t)n * C_DIM + o) * (size_t)S_DIM + s0 + mf * 16 + l4 * 4;
      float4 xv = *(const float4*)(x + idx);
      float4 r;
      r.x = xv.x + acc[mf][nf][0];
      r.y = xv.y + acc[mf][nf][1];
      r.z = xv.z + acc[mf][nf][2];
      r.w = xv.w + acc[mf][nf][3];
      *(float4*)(out + idx) = r;
    }
  }
}

// ---------------------------------------------------------------------------
extern "C" void kernel_launch(void* const* d_in, const int* in_sizes, int n_in,
                              void* d_out, int out_size, void* d_ws, size_t ws_size,
                              hipStream_t stream) {
  const float* x   = (const float*)d_in[0];
  const float* Wth = (const float*)d_in[1];
  const float* Wph = (const float*)d_in[2];
  const float* Wpr = (const float*)d_in[3];
  float* out = (float*)d_out;

  short* q_ws  = (short*)d_ws;                              // 4 MB  [N,S,E]
  short* k_ws  = q_ws  + (size_t)4 * S_DIM * E_DIM;         // 4 MB  [N,S,E]
  short* xb_ws = k_ws  + (size_t)4 * S_DIM * E_DIM;         // 8 MB  [N,C,S]
  short* y_ws  = xb_ws + (size_t)4 * C_DIM * S_DIM;         // 8 MB  [N,S,C]
  short* wb_ws = y_ws  + (size_t)4 * S_DIM * C_DIM;         // 256 KB bf16 weights

  float qscale = 1.4426950408889634f / sqrtf(128.0f);       // log2(e)/sqrt(E)

  cast_w_kernel<<<128, 256, 0, stream>>>(Wth, Wph, Wpr, wb_ws);
  mix_kernel<<<512, 256, 0, stream>>>(x, wb_ws, q_ws, k_ws, xb_ws, qscale);
  attn_kernel<<<256, 512, 0, stream>>>(q_ws, k_ws, xb_ws, y_ws);
  proj_kernel<<<512, 256, 0, stream>>>(y_ws, wb_ws + 65536, x, out);
}